// Round 2
// baseline (943.720 us; speedup 1.0000x reference)
//
#include <hip/hip_runtime.h>
#include <math.h>

// Problem constants (fixed by setup_inputs: B=8, h=w=64, C=256)
#define TT 4096
#define HH 64
#define WW 64
#define CC 256
#define UU 8   // scan prefetch depth

// ---------------------------------------------------------------------------
// Kernel 1: fold alpha-weighted {identity, 1x1, 3x3, 5x5} depthwise convs into
// one effective 5x5 kernel. Layout weff[k][c] (k=0..24) for coalesced reads.
__global__ __launch_bounds__(256)
void build_weff(const float* __restrict__ alpha,
                const float* __restrict__ cw1,
                const float* __restrict__ cw3,
                const float* __restrict__ cw5,
                float* __restrict__ weff) {
    int k = blockIdx.x;       // 0..24
    int c = threadIdx.x;      // 0..255
    float a0 = alpha[0], a1 = alpha[1], a2 = alpha[2], a3 = alpha[3];
    float v = a3 * cw5[c * 25 + k];
    int ky = k / 5, kx = k % 5;
    if (ky >= 1 && ky <= 3 && kx >= 1 && kx <= 3)
        v += a2 * cw3[c * 9 + (ky - 1) * 3 + (kx - 1)];
    if (k == 12) v += a1 * cw1[c] + a0;   // center: 1x1 conv + identity
    weff[k * CC + c] = v;
}

// ---------------------------------------------------------------------------
// Kernel 2: depthwise 5x5 conv, zero padding, directly in [B,T,C] layout
// (t = y*W + x). One block per pixel, one thread per channel (coalesced).
__global__ __launch_bounds__(256)
void omni_conv(const float* __restrict__ x,
               const float* __restrict__ weff,
               float* __restrict__ xf) {
    int t = blockIdx.x;            // b*T + y*W + x
    int c = threadIdx.x;
    int b = t / TT;
    int yx = t - b * TT;
    int y = yx / WW, xx = yx - y * WW;
    const float* xb = x + (size_t)b * TT * CC;
    float acc = 0.f;
    #pragma unroll
    for (int ky = 0; ky < 5; ++ky) {
        int yy = y + ky - 2;
        if (yy < 0 || yy >= HH) continue;
        #pragma unroll
        for (int kx = 0; kx < 5; ++kx) {
            int xxx = xx + kx - 2;
            if (xxx < 0 || xxx >= WW) continue;
            acc += weff[(ky * 5 + kx) * CC + c] * xb[((size_t)yy * WW + xxx) * CC + c];
        }
    }
    xf[(size_t)t * CC + c] = acc;
}

// ---------------------------------------------------------------------------
// fp32 GEMM core: C[m,n] = sum_k A[m,k] * W[n,k] ("NT", both row-major in k).
// BM=BN=128, BK=32, 256 threads, 8x8 outputs/thread.
// A split at k=256 between A0/A1 (row stride 256 each) for the KTOT=512 case.
// Thread (tx,ty), tx=tid&15, ty=tid>>4: rows ty*8..+7, cols {tx*4..+3, 64+tx*4..+3}
// -> W-tile LDS reads are 16 unique 16B-contiguous addrs (conflict-free),
//    A-tile reads are quarter-wave broadcasts.
template<int KTOT>
__device__ __forceinline__ void gemm_core(const float* __restrict__ A0,
                                          const float* __restrict__ A1,
                                          const float* __restrict__ W,
                                          float* __restrict__ Cout,
                                          int m_blk, int n_blk, bool act) {
    __shared__ __align__(16) float As[32][128];
    __shared__ __align__(16) float Ws_[32][128];
    int tid = threadIdx.x;
    int tx = tid & 15, ty = tid >> 4;
    float acc[8][8];
    #pragma unroll
    for (int i = 0; i < 8; ++i)
        #pragma unroll
        for (int j = 0; j < 8; ++j) acc[i][j] = 0.f;

    for (int kt0 = 0; kt0 < KTOT; kt0 += 32) {
        // A tile: 128 rows x 32 k, stored transposed As[k][m]
        #pragma unroll
        for (int i = 0; i < 4; ++i) {
            int f = tid + i * 256;
            int row = f >> 3;
            int k0 = (f & 7) * 4;
            int kkg = kt0 + k0;
            const float* src;
            if (KTOT == 256 || kt0 + 31 < 256) {
                src = A0 + (size_t)(m_blk + row) * 256 + kkg;
            } else {
                src = A1 + (size_t)(m_blk + row) * 256 + (kkg - 256);
            }
            float4 av = *(const float4*)src;
            As[k0 + 0][row] = av.x;
            As[k0 + 1][row] = av.y;
            As[k0 + 2][row] = av.z;
            As[k0 + 3][row] = av.w;
        }
        // W tile: 128 rows x 32 k, stored transposed Ws_[k][n]
        #pragma unroll
        for (int i = 0; i < 4; ++i) {
            int f = tid + i * 256;
            int row = f >> 3;
            int k0 = (f & 7) * 4;
            float4 wv = *(const float4*)(W + (size_t)(n_blk + row) * KTOT + kt0 + k0);
            Ws_[k0 + 0][row] = wv.x;
            Ws_[k0 + 1][row] = wv.y;
            Ws_[k0 + 2][row] = wv.z;
            Ws_[k0 + 3][row] = wv.w;
        }
        __syncthreads();
        #pragma unroll
        for (int kk = 0; kk < 32; ++kk) {
            float4 a0 = *(const float4*)&As[kk][ty * 8];
            float4 a1 = *(const float4*)&As[kk][ty * 8 + 4];
            float4 w0 = *(const float4*)&Ws_[kk][tx * 4];
            float4 w1 = *(const float4*)&Ws_[kk][64 + tx * 4];
            float am[8] = {a0.x, a0.y, a0.z, a0.w, a1.x, a1.y, a1.z, a1.w};
            float wn[8] = {w0.x, w0.y, w0.z, w0.w, w1.x, w1.y, w1.z, w1.w};
            #pragma unroll
            for (int i = 0; i < 8; ++i)
                #pragma unroll
                for (int j = 0; j < 8; ++j)
                    acc[i][j] = fmaf(am[i], wn[j], acc[i][j]);
        }
        __syncthreads();
    }
    #pragma unroll
    for (int i = 0; i < 8; ++i) {
        int m = m_blk + ty * 8 + i;
        float vo[8];
        #pragma unroll
        for (int j = 0; j < 8; ++j) {
            float v = acc[i][j];
            if (act) v = 1.f / (1.f + __expf(-v));
            vo[j] = v;
        }
        *(float4*)(Cout + (size_t)m * 256 + n_blk + tx * 4)      = make_float4(vo[0], vo[1], vo[2], vo[3]);
        *(float4*)(Cout + (size_t)m * 256 + n_blk + 64 + tx * 4) = make_float4(vo[4], vo[5], vo[6], vo[7]);
    }
}

// Fused k/v/r projections: grid (M/128, 6); y>>1 selects matrix, y&1 selects
// the 128-wide N half. Sigmoid fused into the r epilogue.
__global__ __launch_bounds__(256, 2)
void gemm_kvr(const float* __restrict__ xf,
              const float* __restrict__ Wk, const float* __restrict__ Wv,
              const float* __restrict__ Wr,
              float* __restrict__ kb, float* __restrict__ vb, float* __restrict__ rb) {
    int mat = blockIdx.y >> 1;
    int n_blk = (blockIdx.y & 1) * 128;
    const float* W = (mat == 0) ? Wk : (mat == 1) ? Wv : Wr;
    float* C = (mat == 0) ? kb : (mat == 1) ? vb : rb;
    gemm_core<256>(xf, xf, W, C, blockIdx.x * 128, n_blk, mat == 2);
}

// Output projection: A = [xs0 | xs1] (k split at 256), W = Wo [256,512].
__global__ __launch_bounds__(256, 2)
void gemm_out(const float* __restrict__ xs0, const float* __restrict__ xs1,
              const float* __restrict__ Wo, float* __restrict__ out) {
    gemm_core<512>(xs0, xs1, Wo, out, blockIdx.x * 128, blockIdx.y * 128, false);
}

// ---------------------------------------------------------------------------
// Kernel 4: WKV recurrence. Grid (B, 2): blockIdx.y = direction.
// dir 0 scans k/v at t (row-major); dir 1 at src(t) = (t%64)*64 + t/64
// (the 'b (h w) -> b (w h)' reorder) -- k1/v1 never materialized.
// sr is NOT permuted for dir 1 (reference concatenates [sr, sr] unpermuted).
// Output xs*srs written into per-direction halves xs0/xs1 [B,T,C].
__global__ __launch_bounds__(256)
void wkv_scan(const float* __restrict__ kin, const float* __restrict__ vin,
              const float* __restrict__ srin,
              const float* __restrict__ sdecay, const float* __restrict__ sfirst,
              float* __restrict__ xs0, float* __restrict__ xs1) {
    int b = blockIdx.x;
    int dir = blockIdx.y;
    int c = threadIdx.x;
    int d = dir * CC + c;
    const float inv_T = 1.0f / (float)TT;
    float u  = sfirst[d] * inv_T;
    float wd = -expf(sdecay[d] * inv_T);

    const float* kb  = kin  + (size_t)b * TT * CC + c;
    const float* vb  = vin  + (size_t)b * TT * CC + c;
    const float* srb = srin + (size_t)b * TT * CC + c;
    float* xout = (dir ? xs1 : xs0) + (size_t)b * TT * CC + c;

    float aa = 0.f, bb = 0.f, pp = -1e38f;

    float kA[UU], vA[UU], sA[UU], kB[UU], vB[UU], sB[UU];

#define SRC_OFF(t_) ((size_t)(dir ? (((t_) & 63) * 64 + ((t_) >> 6)) : (t_)) * CC)

#define LOADX(KR, VR, SR, T0) do {                          \
        _Pragma("unroll")                                   \
        for (int i_ = 0; i_ < UU; ++i_) {                   \
            int t_ = (T0) + i_;                             \
            size_t o_ = SRC_OFF(t_);                        \
            KR[i_] = kb[o_];                                \
            VR[i_] = vb[o_];                                \
            SR[i_] = srb[(size_t)t_ * CC];                  \
        }                                                   \
    } while (0)

#define STEPX(KR, VR, SR, T0) do {                          \
        _Pragma("unroll")                                   \
        for (int i_ = 0; i_ < UU; ++i_) {                   \
            float kt = KR[i_], vt = VR[i_], st = SR[i_];    \
            float ww = u + kt;                              \
            float p  = fmaxf(pp, ww);                       \
            float e1 = __expf(pp - p);                      \
            float e2 = __expf(ww - p);                      \
            float out = (e1 * aa + e2 * vt) / (e1 * bb + e2); \
            float ww2 = pp + wd;                            \
            float p2  = fmaxf(ww2, kt);                     \
            float f1  = __expf(ww2 - p2);                   \
            float f2  = __expf(kt - p2);                    \
            aa = f1 * aa + f2 * vt;                         \
            bb = f1 * bb + f2;                              \
            pp = p2;                                        \
            xout[(size_t)((T0) + i_) * CC] = out * st;      \
        }                                                   \
    } while (0)

    LOADX(kA, vA, sA, 0);
    for (int t0 = 0; t0 < TT; t0 += 2 * UU) {
        LOADX(kB, vB, sB, t0 + UU);
        STEPX(kA, vA, sA, t0);
        if (t0 + 2 * UU < TT) LOADX(kA, vA, sA, t0 + 2 * UU);
        STEPX(kB, vB, sB, t0 + UU);
    }
#undef SRC_OFF
#undef LOADX
#undef STEPX
}

// ---------------------------------------------------------------------------
extern "C" void kernel_launch(void* const* d_in, const int* in_sizes, int n_in,
                              void* d_out, int out_size, void* d_ws, size_t ws_size,
                              hipStream_t stream) {
    const float* x     = (const float*)d_in[0];
    const float* alpha = (const float*)d_in[1];
    const float* cw1   = (const float*)d_in[2];
    const float* cw3   = (const float*)d_in[3];
    const float* cw5   = (const float*)d_in[4];
    const float* Wk    = (const float*)d_in[5];
    const float* Wv    = (const float*)d_in[6];
    const float* Wr    = (const float*)d_in[7];
    const float* Wo    = (const float*)d_in[8];
    const float* sd    = (const float*)d_in[9];
    const float* sf    = (const float*)d_in[10];
    (void)n_in; (void)out_size; (void)ws_size;

    int B = in_sizes[0] / (TT * CC);
    int M = B * TT;
    size_t MC = (size_t)M * CC;

    float* ws    = (float*)d_ws;
    float* weff  = ws;            // 25*256 floats (pad to 8192)
    float* xf    = ws + 8192;     // MC   (reused as xs0 after projections)
    float* kbuf  = xf + MC;       // MC
    float* vbuf  = kbuf + MC;     // MC
    float* srbuf = vbuf + MC;     // MC
    float* xs1   = srbuf + MC;    // MC   -> total ~168 MB for B=8

    build_weff<<<25, CC, 0, stream>>>(alpha, cw1, cw3, cw5, weff);
    omni_conv<<<M, CC, 0, stream>>>(x, weff, xf);

    // fused k/v/r projections (A-tile shared per block; sigmoid on r)
    gemm_kvr<<<dim3(M / 128, 6), 256, 0, stream>>>(xf, Wk, Wv, Wr, kbuf, vbuf, srbuf);

    wkv_scan<<<dim3(B, 2), CC, 0, stream>>>(kbuf, vbuf, srbuf, sd, sf, xf, xs1);

    // out[b,t,c] = sum_d xs[b,t,d] * Wo[c,d]  (A split: xs0 = xf, xs1)
    gemm_out<<<dim3(M / 128, 2), 256, 0, stream>>>(xf, xs1, Wo, (float*)d_out);
}

// Round 3
// 548.715 us; speedup vs baseline: 1.7199x; 1.7199x over previous
//
#include <hip/hip_runtime.h>
#include <math.h>

// Problem constants (fixed by setup_inputs: B=8, h=w=64, C=256)
#define TT 4096
#define HH 64
#define WW 64
#define CC 256
#define NCH 64   // scan chunks
#define LCH 64   // steps per chunk (NCH*LCH == TT)

// ---------------------------------------------------------------------------
// Kernel 1: fold alpha-weighted {identity, 1x1, 3x3, 5x5} depthwise convs into
// one effective 5x5 kernel. Layout weff[k][c] (k=0..24) for coalesced reads.
__global__ __launch_bounds__(256)
void build_weff(const float* __restrict__ alpha,
                const float* __restrict__ cw1,
                const float* __restrict__ cw3,
                const float* __restrict__ cw5,
                float* __restrict__ weff) {
    int k = blockIdx.x;       // 0..24
    int c = threadIdx.x;      // 0..255
    float a0 = alpha[0], a1 = alpha[1], a2 = alpha[2], a3 = alpha[3];
    float v = a3 * cw5[c * 25 + k];
    int ky = k / 5, kx = k % 5;
    if (ky >= 1 && ky <= 3 && kx >= 1 && kx <= 3)
        v += a2 * cw3[c * 9 + (ky - 1) * 3 + (kx - 1)];
    if (k == 12) v += a1 * cw1[c] + a0;   // center: 1x1 conv + identity
    weff[k * CC + c] = v;
}

// ---------------------------------------------------------------------------
// Kernel 2: depthwise 5x5 conv, zero padding, directly in [B,T,C] layout
// (t = y*W + x). One block per pixel, one thread per channel (coalesced).
__global__ __launch_bounds__(256)
void omni_conv(const float* __restrict__ x,
               const float* __restrict__ weff,
               float* __restrict__ xf) {
    int t = blockIdx.x;            // b*T + y*W + x
    int c = threadIdx.x;
    int b = t / TT;
    int yx = t - b * TT;
    int y = yx / WW, xx = yx - y * WW;
    const float* xb = x + (size_t)b * TT * CC;
    float acc = 0.f;
    #pragma unroll
    for (int ky = 0; ky < 5; ++ky) {
        int yy = y + ky - 2;
        if (yy < 0 || yy >= HH) continue;
        #pragma unroll
        for (int kx = 0; kx < 5; ++kx) {
            int xxx = xx + kx - 2;
            if (xxx < 0 || xxx >= WW) continue;
            acc += weff[(ky * 5 + kx) * CC + c] * xb[((size_t)yy * WW + xxx) * CC + c];
        }
    }
    xf[(size_t)t * CC + c] = acc;
}

// ---------------------------------------------------------------------------
// fp32 GEMM core: C[m,n] = sum_k A[m,k] * W[n,k] ("NT", both row-major in k).
// BM=BN=128, BK=32, 256 threads, 8x8 outputs/thread.
template<int KTOT>
__device__ __forceinline__ void gemm_core(const float* __restrict__ A0,
                                          const float* __restrict__ A1,
                                          const float* __restrict__ W,
                                          float* __restrict__ Cout,
                                          int m_blk, int n_blk, bool act) {
    __shared__ __align__(16) float As[32][128];
    __shared__ __align__(16) float Ws_[32][128];
    int tid = threadIdx.x;
    int tx = tid & 15, ty = tid >> 4;
    float acc[8][8];
    #pragma unroll
    for (int i = 0; i < 8; ++i)
        #pragma unroll
        for (int j = 0; j < 8; ++j) acc[i][j] = 0.f;

    for (int kt0 = 0; kt0 < KTOT; kt0 += 32) {
        #pragma unroll
        for (int i = 0; i < 4; ++i) {
            int f = tid + i * 256;
            int row = f >> 3;
            int k0 = (f & 7) * 4;
            int kkg = kt0 + k0;
            const float* src;
            if (KTOT == 256 || kt0 + 31 < 256) {
                src = A0 + (size_t)(m_blk + row) * 256 + kkg;
            } else {
                src = A1 + (size_t)(m_blk + row) * 256 + (kkg - 256);
            }
            float4 av = *(const float4*)src;
            As[k0 + 0][row] = av.x;
            As[k0 + 1][row] = av.y;
            As[k0 + 2][row] = av.z;
            As[k0 + 3][row] = av.w;
        }
        #pragma unroll
        for (int i = 0; i < 4; ++i) {
            int f = tid + i * 256;
            int row = f >> 3;
            int k0 = (f & 7) * 4;
            float4 wv = *(const float4*)(W + (size_t)(n_blk + row) * KTOT + kt0 + k0);
            Ws_[k0 + 0][row] = wv.x;
            Ws_[k0 + 1][row] = wv.y;
            Ws_[k0 + 2][row] = wv.z;
            Ws_[k0 + 3][row] = wv.w;
        }
        __syncthreads();
        #pragma unroll
        for (int kk = 0; kk < 32; ++kk) {
            float4 a0 = *(const float4*)&As[kk][ty * 8];
            float4 a1 = *(const float4*)&As[kk][ty * 8 + 4];
            float4 w0 = *(const float4*)&Ws_[kk][tx * 4];
            float4 w1 = *(const float4*)&Ws_[kk][64 + tx * 4];
            float am[8] = {a0.x, a0.y, a0.z, a0.w, a1.x, a1.y, a1.z, a1.w};
            float wn[8] = {w0.x, w0.y, w0.z, w0.w, w1.x, w1.y, w1.z, w1.w};
            #pragma unroll
            for (int i = 0; i < 8; ++i)
                #pragma unroll
                for (int j = 0; j < 8; ++j)
                    acc[i][j] = fmaf(am[i], wn[j], acc[i][j]);
        }
        __syncthreads();
    }
    #pragma unroll
    for (int i = 0; i < 8; ++i) {
        int m = m_blk + ty * 8 + i;
        float vo[8];
        #pragma unroll
        for (int j = 0; j < 8; ++j) {
            float v = acc[i][j];
            if (act) v = 1.f / (1.f + __expf(-v));
            vo[j] = v;
        }
        *(float4*)(Cout + (size_t)m * 256 + n_blk + tx * 4)      = make_float4(vo[0], vo[1], vo[2], vo[3]);
        *(float4*)(Cout + (size_t)m * 256 + n_blk + 64 + tx * 4) = make_float4(vo[4], vo[5], vo[6], vo[7]);
    }
}

// Fused k/v/r projections: grid (M/128, 6); y>>1 selects matrix, y&1 selects
// the 128-wide N half. Sigmoid fused into the r epilogue.
__global__ __launch_bounds__(256, 2)
void gemm_kvr(const float* __restrict__ xf,
              const float* __restrict__ Wk, const float* __restrict__ Wv,
              const float* __restrict__ Wr,
              float* __restrict__ kb, float* __restrict__ vb, float* __restrict__ rb) {
    int mat = blockIdx.y >> 1;
    int n_blk = (blockIdx.y & 1) * 128;
    const float* W = (mat == 0) ? Wk : (mat == 1) ? Wv : Wr;
    float* C = (mat == 0) ? kb : (mat == 1) ? vb : rb;
    gemm_core<256>(xf, xf, W, C, blockIdx.x * 128, n_blk, mat == 2);
}

// Output projection: A = [xs0 | xs1] (k split at 256), W = Wo [256,512].
__global__ __launch_bounds__(256, 2)
void gemm_out(const float* __restrict__ xs0, const float* __restrict__ xs1,
              const float* __restrict__ Wo, float* __restrict__ out) {
    gemm_core<512>(xs0, xs1, Wo, out, blockIdx.x * 128, blockIdx.y * 128, false);
}

// ---------------------------------------------------------------------------
// Chunk-parallel WKV. State rep: (a, b, p) meaning unnormalized (a*e^p, b*e^p).
// Per-step: p2=max(p+wd, kt); a=e^{p+wd-p2}a+e^{kt-p2}v; b=e^{p+wd-p2}b+e^{kt-p2}.
// dir 0 reads k/v at t; dir 1 at src(t)=(t%64)*64+t/64. sr always at t.
//
// Pass 1: per (b,dir,chunk): local state over LCH steps from (0,0,-1e38).
__global__ __launch_bounds__(256)
void wkv_pass1(const float* __restrict__ kin, const float* __restrict__ vin,
               const float* __restrict__ sdecay,
               float* __restrict__ cs_a, float* __restrict__ cs_b,
               float* __restrict__ cs_p) {
    int ch = blockIdx.x, dir = blockIdx.y, bb = blockIdx.z, c = threadIdx.x;
    float wd = -expf(sdecay[dir * CC + c] * (1.f / TT));
    const float* kb = kin + (size_t)bb * TT * CC + c;
    const float* vb = vin + (size_t)bb * TT * CC + c;
    float a = 0.f, b = 0.f, p = -1e38f;
    for (int i0 = 0; i0 < LCH; i0 += 8) {
        float k8[8], v8[8];
        #pragma unroll
        for (int i = 0; i < 8; ++i) {
            int ii = i0 + i;
            int src = dir ? (ii * WW + ch) : (ch * LCH + ii);
            k8[i] = kb[(size_t)src * CC];
            v8[i] = vb[(size_t)src * CC];
        }
        #pragma unroll
        for (int i = 0; i < 8; ++i) {
            float kt = k8[i], vt = v8[i];
            float ww2 = p + wd;
            float p2 = fmaxf(ww2, kt);
            float f1 = __expf(ww2 - p2), f2 = __expf(kt - p2);
            a = f1 * a + f2 * vt; b = f1 * b + f2; p = p2;
        }
    }
    size_t o = ((size_t)(bb * 2 + dir) * NCH + ch) * CC + c;
    cs_a[o] = a; cs_b[o] = b; cs_p[o] = p;
}

// Pass 2: serial exclusive prefix over chunk states (combine with decay L*wd).
__global__ __launch_bounds__(256)
void wkv_pass2(const float* __restrict__ sdecay,
               float* __restrict__ cs_a, float* __restrict__ cs_b,
               float* __restrict__ cs_p) {
    int bb = blockIdx.x, dir = blockIdx.y, c = threadIdx.x;
    float wd = -expf(sdecay[dir * CC + c] * (1.f / TT));
    float Ld = (float)LCH * wd;
    float a = 0.f, b = 0.f, p = -1e38f;
    size_t base = (size_t)(bb * 2 + dir) * NCH * CC + c;
    for (int ch = 0; ch < NCH; ++ch) {
        size_t o = base + (size_t)ch * CC;
        float al = cs_a[o], bl = cs_b[o], pl = cs_p[o];
        cs_a[o] = a; cs_b[o] = b; cs_p[o] = p;   // entry state for chunk ch
        float sh = p + Ld;
        float pn = fmaxf(sh, pl);
        float e1 = __expf(sh - pn), e2 = __expf(pl - pn);
        a = e1 * a + e2 * al; b = e1 * b + e2 * bl; p = pn;
    }
}

// Pass 3: re-run each chunk from its entry state, emitting out*sr.
__global__ __launch_bounds__(256)
void wkv_pass3(const float* __restrict__ kin, const float* __restrict__ vin,
               const float* __restrict__ srin,
               const float* __restrict__ sdecay, const float* __restrict__ sfirst,
               const float* __restrict__ cs_a, const float* __restrict__ cs_b,
               const float* __restrict__ cs_p,
               float* __restrict__ xs0, float* __restrict__ xs1) {
    int ch = blockIdx.x, dir = blockIdx.y, bb = blockIdx.z, c = threadIdx.x;
    int d = dir * CC + c;
    float u  = sfirst[d] * (1.f / TT);
    float wd = -expf(sdecay[d] * (1.f / TT));
    size_t so = ((size_t)(bb * 2 + dir) * NCH + ch) * CC + c;
    float a = cs_a[so], b = cs_b[so], p = cs_p[so];
    const float* kb  = kin  + (size_t)bb * TT * CC + c;
    const float* vb  = vin  + (size_t)bb * TT * CC + c;
    const float* srb = srin + (size_t)bb * TT * CC + c;
    float* xout = (dir ? xs1 : xs0) + (size_t)bb * TT * CC + c;
    for (int i0 = 0; i0 < LCH; i0 += 8) {
        float k8[8], v8[8], s8[8];
        #pragma unroll
        for (int i = 0; i < 8; ++i) {
            int ii = i0 + i;
            int t = ch * LCH + ii;
            int src = dir ? (ii * WW + ch) : t;
            k8[i] = kb[(size_t)src * CC];
            v8[i] = vb[(size_t)src * CC];
            s8[i] = srb[(size_t)t * CC];
        }
        #pragma unroll
        for (int i = 0; i < 8; ++i) {
            int t = ch * LCH + i0 + i;
            float kt = k8[i], vt = v8[i];
            float ww = u + kt;
            float q  = fmaxf(p, ww);
            float e1 = __expf(p - q), e2 = __expf(ww - q);
            float out = (e1 * a + e2 * vt) / (e1 * b + e2);
            xout[(size_t)t * CC] = out * s8[i];
            float ww2 = p + wd;
            float p2  = fmaxf(ww2, kt);
            float f1 = __expf(ww2 - p2), f2 = __expf(kt - p2);
            a = f1 * a + f2 * vt; b = f1 * b + f2; p = p2;
        }
    }
}

// ---------------------------------------------------------------------------
extern "C" void kernel_launch(void* const* d_in, const int* in_sizes, int n_in,
                              void* d_out, int out_size, void* d_ws, size_t ws_size,
                              hipStream_t stream) {
    const float* x     = (const float*)d_in[0];
    const float* alpha = (const float*)d_in[1];
    const float* cw1   = (const float*)d_in[2];
    const float* cw3   = (const float*)d_in[3];
    const float* cw5   = (const float*)d_in[4];
    const float* Wk    = (const float*)d_in[5];
    const float* Wv    = (const float*)d_in[6];
    const float* Wr    = (const float*)d_in[7];
    const float* Wo    = (const float*)d_in[8];
    const float* sd    = (const float*)d_in[9];
    const float* sf    = (const float*)d_in[10];
    (void)n_in; (void)out_size; (void)ws_size;

    int B = in_sizes[0] / (TT * CC);
    int M = B * TT;
    size_t MC = (size_t)M * CC;

    float* ws    = (float*)d_ws;
    float* weff  = ws;            // 25*256 floats (pad to 8192)
    float* xf    = ws + 8192;     // MC   (reused as xs0 after projections)
    float* kbuf  = xf + MC;       // MC
    float* vbuf  = kbuf + MC;     // MC
    float* srbuf = vbuf + MC;     // MC
    float* xs1   = srbuf + MC;    // MC

    // chunk states live in d_out (3 MB of 33.5 MB); dead before gemm_out writes it
    size_t SC = (size_t)B * 2 * NCH * CC;
    float* cs_a = (float*)d_out;
    float* cs_b = cs_a + SC;
    float* cs_p = cs_b + SC;

    build_weff<<<25, CC, 0, stream>>>(alpha, cw1, cw3, cw5, weff);
    omni_conv<<<M, CC, 0, stream>>>(x, weff, xf);

    // fused k/v/r projections (A-tile shared per block; sigmoid on r)
    gemm_kvr<<<dim3(M / 128, 6), 256, 0, stream>>>(xf, Wk, Wv, Wr, kbuf, vbuf, srbuf);

    // chunk-parallel WKV scan
    wkv_pass1<<<dim3(NCH, 2, B), 256, 0, stream>>>(kbuf, vbuf, sd, cs_a, cs_b, cs_p);
    wkv_pass2<<<dim3(B, 2), 256, 0, stream>>>(sd, cs_a, cs_b, cs_p);
    wkv_pass3<<<dim3(NCH, 2, B), 256, 0, stream>>>(kbuf, vbuf, srbuf, sd, sf,
                                                   cs_a, cs_b, cs_p, xf, xs1);

    // out[b,t,c] = sum_d xs[b,t,d] * Wo[c,d]  (A split: xs0 = xf, xs1)
    gemm_out<<<dim3(M / 128, 2), 256, 0, stream>>>(xf, xs1, Wo, (float*)d_out);
}

// Round 4
// 364.555 us; speedup vs baseline: 2.5887x; 1.5052x over previous
//
#include <hip/hip_runtime.h>
#include <math.h>
#include <stdint.h>

// Problem constants (fixed by setup_inputs: B=8, h=w=64, C=256)
#define TT 4096
#define HH 64
#define WW 64
#define CC 256
#define NCH 64
#define LCH 64

typedef __bf16 bf16x8 __attribute__((ext_vector_type(8)));
typedef float  f32x4  __attribute__((ext_vector_type(4)));

__device__ __forceinline__ unsigned short f2bf(float x) {
    uint32_t u = __float_as_uint(x);
    u = (u + 0x7fffu + ((u >> 16) & 1u)) >> 16;
    return (unsigned short)u;
}
__device__ __forceinline__ float bf2f(unsigned short h) {
    return __uint_as_float(((uint32_t)h) << 16);
}

// ---------------------------------------------------------------------------
// Fold alpha-weighted {id, 1x1, 3x3, 5x5} depthwise convs into one 5x5 kernel.
__global__ __launch_bounds__(256)
void build_weff(const float* __restrict__ alpha,
                const float* __restrict__ cw1,
                const float* __restrict__ cw3,
                const float* __restrict__ cw5,
                float* __restrict__ weff) {
    int k = blockIdx.x;       // 0..24
    int c = threadIdx.x;      // 0..255
    float a0 = alpha[0], a1 = alpha[1], a2 = alpha[2], a3 = alpha[3];
    float v = a3 * cw5[c * 25 + k];
    int ky = k / 5, kx = k % 5;
    if (ky >= 1 && ky <= 3 && kx >= 1 && kx <= 3)
        v += a2 * cw3[c * 9 + (ky - 1) * 3 + (kx - 1)];
    if (k == 12) v += a1 * cw1[c] + a0;
    weff[k * CC + c] = v;
}

// Split Wk/Wv/Wr into [hi | lo] bf16 rows (LDW=512).
__global__ __launch_bounds__(256)
void prep_w(const float* __restrict__ Wk, const float* __restrict__ Wv,
            const float* __restrict__ Wr,
            unsigned short* __restrict__ W2k, unsigned short* __restrict__ W2v,
            unsigned short* __restrict__ W2r) {
    int n = blockIdx.x, c = threadIdx.x;
    float a;
    unsigned short h;
    a = Wk[n * 256 + c]; h = f2bf(a); W2k[n * 512 + c] = h; W2k[n * 512 + 256 + c] = f2bf(a - bf2f(h));
    a = Wv[n * 256 + c]; h = f2bf(a); W2v[n * 512 + c] = h; W2v[n * 512 + 256 + c] = f2bf(a - bf2f(h));
    a = Wr[n * 256 + c]; h = f2bf(a); W2r[n * 512 + c] = h; W2r[n * 512 + 256 + c] = f2bf(a - bf2f(h));
}

// Split Wo into [hi0 | lo0 | hi1 | lo1] bf16 rows (LDW=1024). Runs after pass3
// (its output overlays the then-dead srbuf slot).
__global__ __launch_bounds__(256)
void prep_wo(const float* __restrict__ Wo, unsigned short* __restrict__ Wo2) {
    int n = blockIdx.x, c = threadIdx.x;
    float a = Wo[n * 512 + c];
    unsigned short h = f2bf(a);
    Wo2[n * 1024 + c] = h; Wo2[n * 1024 + 256 + c] = f2bf(a - bf2f(h));
    float b = Wo[n * 512 + 256 + c];
    unsigned short h2 = f2bf(b);
    Wo2[n * 1024 + 512 + c] = h2; Wo2[n * 1024 + 768 + c] = f2bf(b - bf2f(h2));
}

// ---------------------------------------------------------------------------
// Depthwise 5x5 conv in [B,T,C] layout; output split to [hi | lo] bf16 (LDA=512).
__global__ __launch_bounds__(256)
void omni_conv(const float* __restrict__ x,
               const float* __restrict__ weff,
               unsigned short* __restrict__ A2) {
    int t = blockIdx.x;
    int c = threadIdx.x;
    int b = t / TT;
    int yx = t - b * TT;
    int y = yx / WW, xx = yx - y * WW;
    const float* xb = x + (size_t)b * TT * CC;
    float acc = 0.f;
    #pragma unroll
    for (int ky = 0; ky < 5; ++ky) {
        int yy = y + ky - 2;
        if (yy < 0 || yy >= HH) continue;
        #pragma unroll
        for (int kx = 0; kx < 5; ++kx) {
            int xxx = xx + kx - 2;
            if (xxx < 0 || xxx >= WW) continue;
            acc += weff[(ky * 5 + kx) * CC + c] * xb[((size_t)yy * WW + xxx) * CC + c];
        }
    }
    unsigned short h = f2bf(acc);
    A2[(size_t)t * 512 + c] = h;
    A2[(size_t)t * 512 + 256 + c] = f2bf(acc - bf2f(h));
}

// ---------------------------------------------------------------------------
// bf16x3 MFMA GEMM (NT): C[m,n] = sum_k A[m,k]*W[n,k] in fp32-grade precision.
// A rows are [hi | lo] (512 ushorts); W rows [hi|lo] (512) or [hi0|lo0|hi1|lo1]
// (1024). K-block pairs give Ah*Wh + Al*Wh + Ah*Wl per 256-wide logical block.
// Tile BM=BN=128, BK=64, 4 waves, 4x4 16x16x32 frags/wave.
// LDS staged via global_load_lds(16B) with pre-swizzled global source:
// LDS[r][slot s] = G[r][s ^ (r&7)]  (8-slot XOR, rule #21 both-sides swizzle).
template<int NP, int LDW, int LDC, int KIND>
__device__ __forceinline__ void mfma_core(const unsigned short* __restrict__ A0,
                                          const unsigned short* __restrict__ A1,
                                          const unsigned short* __restrict__ W2,
                                          float* __restrict__ C,
                                          int m_blk, int n_blk, bool act) {
    __shared__ __align__(16) unsigned short As[128 * 64];
    __shared__ __align__(16) unsigned short Bs[128 * 64];
    int tid = threadIdx.x;
    int w = tid >> 6, l = tid & 63;
    int lr = l >> 3, cb = l & 7;        // staging: row-in-8, 16B slot
    int q = l >> 4, rr = l & 15;        // mfma: k-group, row/col-in-16
    int wm = (w & 1) * 64, wn = (w >> 1) * 64;

    f32x4 acc[4][4];
    #pragma unroll
    for (int i = 0; i < 4; ++i)
        #pragma unroll
        for (int j = 0; j < 4; ++j)
            acc[i][j] = (f32x4){0.f, 0.f, 0.f, 0.f};

    #pragma unroll
    for (int p = 0; p < NP; ++p) {
        int pa, pw;
        if (KIND == 0) {
            constexpr int PA[3] = {0, 256, 0};
            constexpr int PW[3] = {0, 0, 256};
            pa = PA[p]; pw = PW[p];
        } else {
            constexpr int PA[6] = {0, 256, 0, 512, 768, 512};
            constexpr int PW[6] = {0, 0, 256, 512, 512, 768};
            pa = PA[p]; pw = PW[p];
        }
        const unsigned short* Ab = (pa >= 512) ? A1 : A0;
        int pa2 = (pa >= 512) ? (pa - 512) : pa;

        for (int bk = 0; bk < 4; ++bk) {
            int aoff = pa2 + bk * 64;
            int woff = pw + bk * 64;
            __syncthreads();   // prev compute done: LDS safe to overwrite
            #pragma unroll
            for (int i = 0; i < 4; ++i) {
                int r = w * 32 + i * 8 + lr;
                int sw = (cb ^ (r & 7)) << 3;
                const unsigned short* ga = Ab + (size_t)(m_blk + r) * 512 + aoff + sw;
                __builtin_amdgcn_global_load_lds(
                    (const __attribute__((address_space(1))) void*)ga,
                    (__attribute__((address_space(3))) void*)&As[(w * 32 + i * 8) * 64],
                    16, 0, 0);
                const unsigned short* gb = W2 + (size_t)(n_blk + r) * LDW + woff + sw;
                __builtin_amdgcn_global_load_lds(
                    (const __attribute__((address_space(1))) void*)gb,
                    (__attribute__((address_space(3))) void*)&Bs[(w * 32 + i * 8) * 64],
                    16, 0, 0);
            }
            __syncthreads();   // staging loads drained (vmcnt0 before barrier)

            bf16x8 af[4][2], bf[4][2];
            #pragma unroll
            for (int f = 0; f < 4; ++f)
                #pragma unroll
                for (int kb = 0; kb < 2; ++kb) {
                    int slot = ((kb * 4 + q) ^ (rr & 7)) << 3;
                    af[f][kb] = *(const bf16x8*)&As[(wm + f * 16 + rr) * 64 + slot];
                    bf[f][kb] = *(const bf16x8*)&Bs[(wn + f * 16 + rr) * 64 + slot];
                }
            #pragma unroll
            for (int kb = 0; kb < 2; ++kb)
                #pragma unroll
                for (int fm = 0; fm < 4; ++fm)
                    #pragma unroll
                    for (int fn = 0; fn < 4; ++fn)
                        acc[fm][fn] = __builtin_amdgcn_mfma_f32_16x16x32_bf16(
                            af[fm][kb], bf[fn][kb], acc[fm][fn], 0, 0, 0);
        }
    }
    // Epilogue: C/D layout col=lane&15, row=(lane>>4)*4+reg (m89-verified).
    #pragma unroll
    for (int fm = 0; fm < 4; ++fm)
        #pragma unroll
        for (int fn = 0; fn < 4; ++fn) {
            int col = n_blk + wn + fn * 16 + rr;
            int row0 = m_blk + wm + fm * 16 + q * 4;
            f32x4 v = acc[fm][fn];
            #pragma unroll
            for (int j = 0; j < 4; ++j) {
                float o = v[j];
                if (act) o = 1.f / (1.f + __expf(-o));
                C[(size_t)(row0 + j) * LDC + col] = o;
            }
        }
}

__global__ __launch_bounds__(256)
void gemm_kvr_mfma(const unsigned short* __restrict__ A2,
                   const unsigned short* __restrict__ W2k,
                   const unsigned short* __restrict__ W2v,
                   const unsigned short* __restrict__ W2r,
                   float* __restrict__ kb, float* __restrict__ vb,
                   float* __restrict__ rb) {
    int mat = blockIdx.y >> 1;
    int n_blk = (blockIdx.y & 1) * 128;
    const unsigned short* W2 = (mat == 0) ? W2k : (mat == 1) ? W2v : W2r;
    float* C = (mat == 0) ? kb : (mat == 1) ? vb : rb;
    mfma_core<3, 512, 256, 0>(A2, A2, W2, C, blockIdx.x * 128, n_blk, mat == 2);
}

__global__ __launch_bounds__(256)
void gemm_out_mfma(const unsigned short* __restrict__ xs0,
                   const unsigned short* __restrict__ xs1,
                   const unsigned short* __restrict__ Wo2,
                   float* __restrict__ out) {
    mfma_core<6, 1024, 256, 1>(xs0, xs1, Wo2, out, blockIdx.x * 128,
                               blockIdx.y * 128, false);
}

// ---------------------------------------------------------------------------
// Chunk-parallel WKV (state (a,b,p) = unnormalized (a*e^p, b*e^p)).
__global__ __launch_bounds__(256)
void wkv_pass1(const float* __restrict__ kin, const float* __restrict__ vin,
               const float* __restrict__ sdecay,
               float* __restrict__ cs_a, float* __restrict__ cs_b,
               float* __restrict__ cs_p) {
    int ch = blockIdx.x, dir = blockIdx.y, bb = blockIdx.z, c = threadIdx.x;
    float wd = -expf(sdecay[dir * CC + c] * (1.f / TT));
    const float* kb = kin + (size_t)bb * TT * CC + c;
    const float* vb = vin + (size_t)bb * TT * CC + c;
    float a = 0.f, b = 0.f, p = -1e38f;
    for (int i0 = 0; i0 < LCH; i0 += 8) {
        float k8[8], v8[8];
        #pragma unroll
        for (int i = 0; i < 8; ++i) {
            int ii = i0 + i;
            int src = dir ? (ii * WW + ch) : (ch * LCH + ii);
            k8[i] = kb[(size_t)src * CC];
            v8[i] = vb[(size_t)src * CC];
        }
        #pragma unroll
        for (int i = 0; i < 8; ++i) {
            float kt = k8[i], vt = v8[i];
            float ww2 = p + wd;
            float p2 = fmaxf(ww2, kt);
            float f1 = __expf(ww2 - p2), f2 = __expf(kt - p2);
            a = f1 * a + f2 * vt; b = f1 * b + f2; p = p2;
        }
    }
    size_t o = ((size_t)(bb * 2 + dir) * NCH + ch) * CC + c;
    cs_a[o] = a; cs_b[o] = b; cs_p[o] = p;
}

__global__ __launch_bounds__(256)
void wkv_pass2(const float* __restrict__ sdecay,
               float* __restrict__ cs_a, float* __restrict__ cs_b,
               float* __restrict__ cs_p) {
    int bb = blockIdx.x, dir = blockIdx.y, c = threadIdx.x;
    float wd = -expf(sdecay[dir * CC + c] * (1.f / TT));
    float Ld = (float)LCH * wd;
    float a = 0.f, b = 0.f, p = -1e38f;
    size_t base = (size_t)(bb * 2 + dir) * NCH * CC + c;
    for (int ch = 0; ch < NCH; ++ch) {
        size_t o = base + (size_t)ch * CC;
        float al = cs_a[o], bl = cs_b[o], pl = cs_p[o];
        cs_a[o] = a; cs_b[o] = b; cs_p[o] = p;
        float sh = p + Ld;
        float pn = fmaxf(sh, pl);
        float e1 = __expf(sh - pn), e2 = __expf(pl - pn);
        a = e1 * a + e2 * al; b = e1 * b + e2 * bl; p = pn;
    }
}

// Pass 3: re-run chunk from entry state; emit (out*sr) split to hi/lo bf16
// into xs2_0 / xs2_1 (row stride 512 ushorts: [hi | lo]).
__global__ __launch_bounds__(256)
void wkv_pass3(const float* __restrict__ kin, const float* __restrict__ vin,
               const float* __restrict__ srin,
               const float* __restrict__ sdecay, const float* __restrict__ sfirst,
               const float* __restrict__ cs_a, const float* __restrict__ cs_b,
               const float* __restrict__ cs_p,
               unsigned short* __restrict__ xs2_0, unsigned short* __restrict__ xs2_1) {
    int ch = blockIdx.x, dir = blockIdx.y, bb = blockIdx.z, c = threadIdx.x;
    int d = dir * CC + c;
    float u  = sfirst[d] * (1.f / TT);
    float wd = -expf(sdecay[d] * (1.f / TT));
    size_t so = ((size_t)(bb * 2 + dir) * NCH + ch) * CC + c;
    float a = cs_a[so], b = cs_b[so], p = cs_p[so];
    const float* kb  = kin  + (size_t)bb * TT * CC + c;
    const float* vb  = vin  + (size_t)bb * TT * CC + c;
    const float* srb = srin + (size_t)bb * TT * CC + c;
    unsigned short* xo = (dir ? xs2_1 : xs2_0) + (size_t)bb * TT * 512 + c;
    for (int i0 = 0; i0 < LCH; i0 += 8) {
        float k8[8], v8[8], s8[8];
        #pragma unroll
        for (int i = 0; i < 8; ++i) {
            int ii = i0 + i;
            int t = ch * LCH + ii;
            int src = dir ? (ii * WW + ch) : t;
            k8[i] = kb[(size_t)src * CC];
            v8[i] = vb[(size_t)src * CC];
            s8[i] = srb[(size_t)t * CC];
        }
        #pragma unroll
        for (int i = 0; i < 8; ++i) {
            int t = ch * LCH + i0 + i;
            float kt = k8[i], vt = v8[i];
            float ww = u + kt;
            float qq = fmaxf(p, ww);
            float e1 = __expf(p - qq), e2 = __expf(ww - qq);
            float out = (e1 * a + e2 * vt) / (e1 * b + e2);
            float os = out * s8[i];
            unsigned short h = f2bf(os);
            xo[(size_t)t * 512] = h;
            xo[(size_t)t * 512 + 256] = f2bf(os - bf2f(h));
            float ww2 = p + wd;
            float p2  = fmaxf(ww2, kt);
            float f1 = __expf(ww2 - p2), f2 = __expf(kt - p2);
            a = f1 * a + f2 * vt; b = f1 * b + f2; p = p2;
        }
    }
}

// ---------------------------------------------------------------------------
extern "C" void kernel_launch(void* const* d_in, const int* in_sizes, int n_in,
                              void* d_out, int out_size, void* d_ws, size_t ws_size,
                              hipStream_t stream) {
    const float* x     = (const float*)d_in[0];
    const float* alpha = (const float*)d_in[1];
    const float* cw1   = (const float*)d_in[2];
    const float* cw3   = (const float*)d_in[3];
    const float* cw5   = (const float*)d_in[4];
    const float* Wk    = (const float*)d_in[5];
    const float* Wv    = (const float*)d_in[6];
    const float* Wr    = (const float*)d_in[7];
    const float* Wo    = (const float*)d_in[8];
    const float* sd    = (const float*)d_in[9];
    const float* sf    = (const float*)d_in[10];
    (void)n_in; (void)out_size; (void)ws_size;

    int B = in_sizes[0] / (TT * CC);
    int M = B * TT;
    size_t S = (size_t)M * 1024;  // bytes per slot (== M*512 ushorts == M*256 floats)

    // ws: 5 equal slots (same footprint as the previous passing round)
    char* wsb = (char*)d_ws;
    unsigned short* A2    = (unsigned short*)wsb;        // slot0; later xs2_0
    float*          kbuf  = (float*)(wsb + 1 * S);
    float*          vbuf  = (float*)(wsb + 2 * S);
    float*          srbuf = (float*)(wsb + 3 * S);
    unsigned short* xs2_1 = (unsigned short*)(wsb + 4 * S);
    unsigned short* Wo2   = (unsigned short*)(wsb + 3 * S); // overlays srbuf post-pass3
    unsigned short* xs2_0 = A2;

    // d_out used as scratch until gemm_out overwrites it entirely:
    // [cs_a 1MB][cs_b 1MB][cs_p 1MB][weff 32KB @3MB][W2k/W2v/W2r @4MB]
    size_t SC = (size_t)B * 2 * NCH * CC;
    char* ob = (char*)d_out;
    float* cs_a = (float*)ob;
    float* cs_b = (float*)(ob + SC * 4);
    float* cs_p = (float*)(ob + 2 * SC * 4);
    float* weff = (float*)(ob + 3 * SC * 4);
    unsigned short* W2k = (unsigned short*)(ob + (4u << 20));
    unsigned short* W2v = (unsigned short*)(ob + (4u << 20) + 262144);
    unsigned short* W2r = (unsigned short*)(ob + (4u << 20) + 524288);

    build_weff<<<25, CC, 0, stream>>>(alpha, cw1, cw3, cw5, weff);
    prep_w<<<256, CC, 0, stream>>>(Wk, Wv, Wr, W2k, W2v, W2r);
    omni_conv<<<M, CC, 0, stream>>>(x, weff, A2);

    gemm_kvr_mfma<<<dim3(M / 128, 6), 256, 0, stream>>>(A2, W2k, W2v, W2r,
                                                        kbuf, vbuf, srbuf);

    wkv_pass1<<<dim3(NCH, 2, B), 256, 0, stream>>>(kbuf, vbuf, sd, cs_a, cs_b, cs_p);
    wkv_pass2<<<dim3(B, 2), 256, 0, stream>>>(sd, cs_a, cs_b, cs_p);
    wkv_pass3<<<dim3(NCH, 2, B), 256, 0, stream>>>(kbuf, vbuf, srbuf, sd, sf,
                                                   cs_a, cs_b, cs_p, xs2_0, xs2_1);

    prep_wo<<<256, CC, 0, stream>>>(Wo, Wo2);
    gemm_out_mfma<<<dim3(M / 128, 2), 256, 0, stream>>>(xs2_0, xs2_1, Wo2,
                                                        (float*)d_out);
}

// Round 6
// 304.453 us; speedup vs baseline: 3.0997x; 1.1974x over previous
//
#include <hip/hip_runtime.h>
#include <math.h>
#include <stdint.h>

// Problem constants (fixed by setup_inputs: B=8, h=w=64, C=256)
#define TT 4096
#define HH 64
#define WW 64
#define CC 256
#define NCH 64
#define LCH 64

typedef __bf16 bf16x8 __attribute__((ext_vector_type(8)));
typedef float  f32x4  __attribute__((ext_vector_type(4)));

__device__ __forceinline__ unsigned short f2bf(float x) {
    uint32_t u = __float_as_uint(x);
    u = (u + 0x7fffu + ((u >> 16) & 1u)) >> 16;
    return (unsigned short)u;
}
__device__ __forceinline__ float bf2f(unsigned short h) {
    return __uint_as_float(((uint32_t)h) << 16);
}

// ---------------------------------------------------------------------------
// Fold alpha-weighted {id, 1x1, 3x3, 5x5} depthwise convs into one 5x5 kernel.
__global__ __launch_bounds__(256)
void build_weff(const float* __restrict__ alpha,
                const float* __restrict__ cw1,
                const float* __restrict__ cw3,
                const float* __restrict__ cw5,
                float* __restrict__ weff) {
    int k = blockIdx.x;       // 0..24
    int c = threadIdx.x;      // 0..255
    float a0 = alpha[0], a1 = alpha[1], a2 = alpha[2], a3 = alpha[3];
    float v = a3 * cw5[c * 25 + k];
    int ky = k / 5, kx = k % 5;
    if (ky >= 1 && ky <= 3 && kx >= 1 && kx <= 3)
        v += a2 * cw3[c * 9 + (ky - 1) * 3 + (kx - 1)];
    if (k == 12) v += a1 * cw1[c] + a0;
    weff[k * CC + c] = v;
}

// Split Wk/Wv/Wr into [hi | lo] bf16 rows (LDW=512).
__global__ __launch_bounds__(256)
void prep_w(const float* __restrict__ Wk, const float* __restrict__ Wv,
            const float* __restrict__ Wr,
            unsigned short* __restrict__ W2k, unsigned short* __restrict__ W2v,
            unsigned short* __restrict__ W2r) {
    int n = blockIdx.x, c = threadIdx.x;
    float a;
    unsigned short h;
    a = Wk[n * 256 + c]; h = f2bf(a); W2k[n * 512 + c] = h; W2k[n * 512 + 256 + c] = f2bf(a - bf2f(h));
    a = Wv[n * 256 + c]; h = f2bf(a); W2v[n * 512 + c] = h; W2v[n * 512 + 256 + c] = f2bf(a - bf2f(h));
    a = Wr[n * 256 + c]; h = f2bf(a); W2r[n * 512 + c] = h; W2r[n * 512 + 256 + c] = f2bf(a - bf2f(h));
}

// Split Wo into [hi0 | lo0 | hi1 | lo1] bf16 rows (LDW=1024).
__global__ __launch_bounds__(256)
void prep_wo(const float* __restrict__ Wo, unsigned short* __restrict__ Wo2) {
    int n = blockIdx.x, c = threadIdx.x;
    float a = Wo[n * 512 + c];
    unsigned short h = f2bf(a);
    Wo2[n * 1024 + c] = h; Wo2[n * 1024 + 256 + c] = f2bf(a - bf2f(h));
    float b = Wo[n * 512 + 256 + c];
    unsigned short h2 = f2bf(b);
    Wo2[n * 1024 + 512 + c] = h2; Wo2[n * 1024 + 768 + c] = f2bf(b - bf2f(h2));
}

// ---------------------------------------------------------------------------
// Depthwise 5x5 conv, sliding-window over y. Block = (x-column, y-strip, b),
// thread = channel. 5x5 register window, 5 new loads per output (vs 25),
// weights in 25 VGPRs. Output split to [hi | lo] bf16 (row stride 512).
__global__ __launch_bounds__(256)
void omni_conv(const float* __restrict__ x,
               const float* __restrict__ weff,
               unsigned short* __restrict__ A2) {
    int xx = blockIdx.x;          // 0..63
    int y0 = blockIdx.y * 32;     // strip start
    int b  = blockIdx.z;
    int c  = threadIdx.x;
    const float* xb = x + (size_t)b * TT * CC + c;
    unsigned short* Ab = A2 + (size_t)b * TT * 512 + c;

    float wk[25];
    #pragma unroll
    for (int k = 0; k < 25; ++k) wk[k] = weff[k * CC + c];

    float win[5][5];  // [row][dx], row i = y-2+i
    #pragma unroll
    for (int i = 0; i < 4; ++i) {
        int yy = y0 - 2 + i;
        #pragma unroll
        for (int dx = 0; dx < 5; ++dx) {
            int xc = xx + dx - 2;
            win[i][dx] = (yy >= 0 && xc >= 0 && xc < WW)
                         ? xb[(size_t)(yy * WW + xc) * CC] : 0.f;
        }
    }
    #pragma unroll
    for (int i = 0; i < 32; ++i) {
        int y = y0 + i;
        int yy = y + 2;
        #pragma unroll
        for (int dx = 0; dx < 5; ++dx) {
            int xc = xx + dx - 2;
            win[4][dx] = (yy < HH && xc >= 0 && xc < WW)
                         ? xb[(size_t)(yy * WW + xc) * CC] : 0.f;
        }
        float acc = 0.f;
        #pragma unroll
        for (int r = 0; r < 5; ++r)
            #pragma unroll
            for (int dx = 0; dx < 5; ++dx)
                acc = fmaf(wk[r * 5 + dx], win[r][dx], acc);
        unsigned short h = f2bf(acc);
        size_t o = (size_t)(y * WW + xx) * 512;
        Ab[o] = h;
        Ab[o + 256] = f2bf(acc - bf2f(h));
        #pragma unroll
        for (int r = 0; r < 4; ++r)
            #pragma unroll
            for (int dx = 0; dx < 5; ++dx)
                win[r][dx] = win[r + 1][dx];
    }
}

// ---------------------------------------------------------------------------
// bf16x3 MFMA GEMM (NT): C[m,n] = sum_k A[m,k]*W[n,k] in fp32-grade precision.
// Tile BM=BN=128, BK=64, 4 waves, 4x4 16x16x32 frags/wave.
// LDS staged via global_load_lds(16B) with pre-swizzled global source (rule #21).
template<int NP, int LDW, int LDC, int KIND>
__device__ __forceinline__ void mfma_core(const unsigned short* __restrict__ A0,
                                          const unsigned short* __restrict__ A1,
                                          const unsigned short* __restrict__ W2,
                                          float* __restrict__ C,
                                          int m_blk, int n_blk, bool act) {
    __shared__ __align__(16) unsigned short As[128 * 64];
    __shared__ __align__(16) unsigned short Bs[128 * 64];
    int tid = threadIdx.x;
    int w = tid >> 6, l = tid & 63;
    int lr = l >> 3, cb = l & 7;
    int q = l >> 4, rr = l & 15;
    int wm = (w & 1) * 64, wn = (w >> 1) * 64;

    f32x4 acc[4][4];
    #pragma unroll
    for (int i = 0; i < 4; ++i)
        #pragma unroll
        for (int j = 0; j < 4; ++j)
            acc[i][j] = (f32x4){0.f, 0.f, 0.f, 0.f};

    #pragma unroll
    for (int p = 0; p < NP; ++p) {
        int pa, pw;
        if (KIND == 0) {
            constexpr int PA[3] = {0, 256, 0};
            constexpr int PW[3] = {0, 0, 256};
            pa = PA[p]; pw = PW[p];
        } else {
            constexpr int PA[6] = {0, 256, 0, 512, 768, 512};
            constexpr int PW[6] = {0, 0, 256, 512, 512, 768};
            pa = PA[p]; pw = PW[p];
        }
        const unsigned short* Ab = (pa >= 512) ? A1 : A0;
        int pa2 = (pa >= 512) ? (pa - 512) : pa;

        for (int bk = 0; bk < 4; ++bk) {
            int aoff = pa2 + bk * 64;
            int woff = pw + bk * 64;
            __syncthreads();
            #pragma unroll
            for (int i = 0; i < 4; ++i) {
                int r = w * 32 + i * 8 + lr;
                int sw = (cb ^ (r & 7)) << 3;
                const unsigned short* ga = Ab + (size_t)(m_blk + r) * 512 + aoff + sw;
                __builtin_amdgcn_global_load_lds(
                    (const __attribute__((address_space(1))) void*)ga,
                    (__attribute__((address_space(3))) void*)&As[(w * 32 + i * 8) * 64],
                    16, 0, 0);
                const unsigned short* gb = W2 + (size_t)(n_blk + r) * LDW + woff + sw;
                __builtin_amdgcn_global_load_lds(
                    (const __attribute__((address_space(1))) void*)gb,
                    (__attribute__((address_space(3))) void*)&Bs[(w * 32 + i * 8) * 64],
                    16, 0, 0);
            }
            __syncthreads();

            bf16x8 af[4][2], bf[4][2];
            #pragma unroll
            for (int f = 0; f < 4; ++f)
                #pragma unroll
                for (int kb = 0; kb < 2; ++kb) {
                    int slot = ((kb * 4 + q) ^ (rr & 7)) << 3;
                    af[f][kb] = *(const bf16x8*)&As[(wm + f * 16 + rr) * 64 + slot];
                    bf[f][kb] = *(const bf16x8*)&Bs[(wn + f * 16 + rr) * 64 + slot];
                }
            #pragma unroll
            for (int kb = 0; kb < 2; ++kb)
                #pragma unroll
                for (int fm = 0; fm < 4; ++fm)
                    #pragma unroll
                    for (int fn = 0; fn < 4; ++fn)
                        acc[fm][fn] = __builtin_amdgcn_mfma_f32_16x16x32_bf16(
                            af[fm][kb], bf[fn][kb], acc[fm][fn], 0, 0, 0);
        }
    }
    #pragma unroll
    for (int fm = 0; fm < 4; ++fm)
        #pragma unroll
        for (int fn = 0; fn < 4; ++fn) {
            int col = n_blk + wn + fn * 16 + rr;
            int row0 = m_blk + wm + fm * 16 + q * 4;
            f32x4 v = acc[fm][fn];
            #pragma unroll
            for (int j = 0; j < 4; ++j) {
                float o = v[j];
                if (act) o = 1.f / (1.f + __expf(-o));
                C[(size_t)(row0 + j) * LDC + col] = o;
            }
        }
}

// Grid (6, M/128): the 6 variants of one m-block are dispatch-adjacent, so
// they hit the same A-panel in L2.
__global__ __launch_bounds__(256)
void gemm_kvr_mfma(const unsigned short* __restrict__ A2,
                   const unsigned short* __restrict__ W2k,
                   const unsigned short* __restrict__ W2v,
                   const unsigned short* __restrict__ W2r,
                   float* __restrict__ kb, float* __restrict__ vb,
                   float* __restrict__ rb) {
    int mat = blockIdx.x >> 1;
    int n_blk = (blockIdx.x & 1) * 128;
    const unsigned short* W2 = (mat == 0) ? W2k : (mat == 1) ? W2v : W2r;
    float* C = (mat == 0) ? kb : (mat == 1) ? vb : rb;
    mfma_core<3, 512, 256, 0>(A2, A2, W2, C, blockIdx.y * 128, n_blk, mat == 2);
}

__global__ __launch_bounds__(256)
void gemm_out_mfma(const unsigned short* __restrict__ xs0,
                   const unsigned short* __restrict__ xs1,
                   const unsigned short* __restrict__ Wo2,
                   float* __restrict__ out) {
    mfma_core<6, 1024, 256, 1>(xs0, xs1, Wo2, out, blockIdx.y * 128,
                               blockIdx.x * 128, false);
}

// ---------------------------------------------------------------------------
// Chunk-parallel WKV (state (a,b,p) = unnormalized (a*e^p, b*e^p)).
__global__ __launch_bounds__(256)
void wkv_pass1(const float* __restrict__ kin, const float* __restrict__ vin,
               const float* __restrict__ sdecay,
               float* __restrict__ cs_a, float* __restrict__ cs_b,
               float* __restrict__ cs_p) {
    int ch = blockIdx.x, dir = blockIdx.y, bb = blockIdx.z, c = threadIdx.x;
    float wd = -expf(sdecay[dir * CC + c] * (1.f / TT));
    const float* kb = kin + (size_t)bb * TT * CC + c;
    const float* vb = vin + (size_t)bb * TT * CC + c;
    float a = 0.f, b = 0.f, p = -1e38f;
    for (int i0 = 0; i0 < LCH; i0 += 8) {
        float k8[8], v8[8];
        #pragma unroll
        for (int i = 0; i < 8; ++i) {
            int ii = i0 + i;
            int src = dir ? (ii * WW + ch) : (ch * LCH + ii);
            k8[i] = kb[(size_t)src * CC];
            v8[i] = vb[(size_t)src * CC];
        }
        #pragma unroll
        for (int i = 0; i < 8; ++i) {
            float kt = k8[i], vt = v8[i];
            float ww2 = p + wd;
            float p2 = fmaxf(ww2, kt);
            float f1 = __expf(ww2 - p2), f2 = __expf(kt - p2);
            a = f1 * a + f2 * vt; b = f1 * b + f2; p = p2;
        }
    }
    size_t o = ((size_t)(bb * 2 + dir) * NCH + ch) * CC + c;
    cs_a[o] = a; cs_b[o] = b; cs_p[o] = p;
}

__global__ __launch_bounds__(256)
void wkv_pass2(const float* __restrict__ sdecay,
               float* __restrict__ cs_a, float* __restrict__ cs_b,
               float* __restrict__ cs_p) {
    int bb = blockIdx.x, dir = blockIdx.y, c = threadIdx.x;
    float wd = -expf(sdecay[dir * CC + c] * (1.f / TT));
    float Ld = (float)LCH * wd;
    float a = 0.f, b = 0.f, p = -1e38f;
    size_t base = (size_t)(bb * 2 + dir) * NCH * CC + c;
    for (int ch = 0; ch < NCH; ++ch) {
        size_t o = base + (size_t)ch * CC;
        float al = cs_a[o], bl = cs_b[o], pl = cs_p[o];
        cs_a[o] = a; cs_b[o] = b; cs_p[o] = p;
        float sh = p + Ld;
        float pn = fmaxf(sh, pl);
        float e1 = __expf(sh - pn), e2 = __expf(pl - pn);
        a = e1 * a + e2 * al; b = e1 * b + e2 * bl; p = pn;
    }
}

// Pass 3: re-run chunk from entry state; emit (out*sr) split to hi/lo bf16.
__global__ __launch_bounds__(256)
void wkv_pass3(const float* __restrict__ kin, const float* __restrict__ vin,
               const float* __restrict__ srin,
               const float* __restrict__ sdecay, const float* __restrict__ sfirst,
               const float* __restrict__ cs_a, const float* __restrict__ cs_b,
               const float* __restrict__ cs_p,
               unsigned short* __restrict__ xs2_0, unsigned short* __restrict__ xs2_1) {
    int ch = blockIdx.x, dir = blockIdx.y, bb = blockIdx.z, c = threadIdx.x;
    int d = dir * CC + c;
    float u  = sfirst[d] * (1.f / TT);
    float wd = -expf(sdecay[d] * (1.f / TT));
    size_t so = ((size_t)(bb * 2 + dir) * NCH + ch) * CC + c;
    float a = cs_a[so], b = cs_b[so], p = cs_p[so];
    const float* kb  = kin  + (size_t)bb * TT * CC + c;
    const float* vb  = vin  + (size_t)bb * TT * CC + c;
    const float* srb = srin + (size_t)bb * TT * CC + c;
    unsigned short* xo = (dir ? xs2_1 : xs2_0) + (size_t)bb * TT * 512 + c;
    for (int i0 = 0; i0 < LCH; i0 += 8) {
        float k8[8], v8[8], s8[8];
        #pragma unroll
        for (int i = 0; i < 8; ++i) {
            int ii = i0 + i;
            int t = ch * LCH + ii;
            int src = dir ? (ii * WW + ch) : t;
            k8[i] = kb[(size_t)src * CC];
            v8[i] = vb[(size_t)src * CC];
            s8[i] = srb[(size_t)t * CC];
        }
        #pragma unroll
        for (int i = 0; i < 8; ++i) {
            int t = ch * LCH + i0 + i;
            float kt = k8[i], vt = v8[i];
            float ww = u + kt;
            float qq = fmaxf(p, ww);
            float e1 = __expf(p - qq), e2 = __expf(ww - qq);
            float out = (e1 * a + e2 * vt) / (e1 * b + e2);
            float os = out * s8[i];
            unsigned short h = f2bf(os);
            xo[(size_t)t * 512] = h;
            xo[(size_t)t * 512 + 256] = f2bf(os - bf2f(h));
            float ww2 = p + wd;
            float p2  = fmaxf(ww2, kt);
            float f1 = __expf(ww2 - p2), f2 = __expf(kt - p2);
            a = f1 * a + f2 * vt; b = f1 * b + f2; p = p2;
        }
    }
}

// ---------------------------------------------------------------------------
extern "C" void kernel_launch(void* const* d_in, const int* in_sizes, int n_in,
                              void* d_out, int out_size, void* d_ws, size_t ws_size,
                              hipStream_t stream) {
    const float* x     = (const float*)d_in[0];
    const float* alpha = (const float*)d_in[1];
    const float* cw1   = (const float*)d_in[2];
    const float* cw3   = (const float*)d_in[3];
    const float* cw5   = (const float*)d_in[4];
    const float* Wk    = (const float*)d_in[5];
    const float* Wv    = (const float*)d_in[6];
    const float* Wr    = (const float*)d_in[7];
    const float* Wo    = (const float*)d_in[8];
    const float* sd    = (const float*)d_in[9];
    const float* sf    = (const float*)d_in[10];
    (void)n_in; (void)out_size; (void)ws_size;

    int B = in_sizes[0] / (TT * CC);
    int M = B * TT;
    size_t S = (size_t)M * 1024;  // bytes per slot

    char* wsb = (char*)d_ws;
    unsigned short* A2    = (unsigned short*)wsb;        // slot0; later xs2_0
    float*          kbuf  = (float*)(wsb + 1 * S);
    float*          vbuf  = (float*)(wsb + 2 * S);
    float*          srbuf = (float*)(wsb + 3 * S);
    unsigned short* xs2_1 = (unsigned short*)(wsb + 4 * S);
    unsigned short* Wo2   = (unsigned short*)(wsb + 3 * S); // overlays srbuf post-pass3
    unsigned short* xs2_0 = A2;

    // d_out as scratch until gemm_out overwrites it entirely.
    size_t SC = (size_t)B * 2 * NCH * CC;
    char* ob = (char*)d_out;
    float* cs_a = (float*)ob;
    float* cs_b = (float*)(ob + SC * 4);
    float* cs_p = (float*)(ob + 2 * SC * 4);
    float* weff = (float*)(ob + 3 * SC * 4);
    unsigned short* W2k = (unsigned short*)(ob + (4u << 20));
    unsigned short* W2v = (unsigned short*)(ob + (4u << 20) + 262144);
    unsigned short* W2r = (unsigned short*)(ob + (4u << 20) + 524288);

    build_weff<<<25, CC, 0, stream>>>(alpha, cw1, cw3, cw5, weff);
    prep_w<<<256, CC, 0, stream>>>(Wk, Wv, Wr, W2k, W2v, W2r);
    omni_conv<<<dim3(WW, 2, B), CC, 0, stream>>>(x, weff, A2);

    gemm_kvr_mfma<<<dim3(6, M / 128), 256, 0, stream>>>(A2, W2k, W2v, W2r,
                                                        kbuf, vbuf, srbuf);

    wkv_pass1<<<dim3(NCH, 2, B), 256, 0, stream>>>(kbuf, vbuf, sd, cs_a, cs_b, cs_p);
    wkv_pass2<<<dim3(B, 2), 256, 0, stream>>>(sd, cs_a, cs_b, cs_p);
    wkv_pass3<<<dim3(NCH, 2, B), 256, 0, stream>>>(kbuf, vbuf, srbuf, sd, sf,
                                                   cs_a, cs_b, cs_p, xs2_0, xs2_1);

    prep_wo<<<256, CC, 0, stream>>>(Wo, Wo2);
    gemm_out_mfma<<<dim3(2, M / 128), 256, 0, stream>>>(xs2_0, xs2_1, Wo2,
                                                        (float*)d_out);
}